// Round 11
// baseline (255.933 us; speedup 1.0000x reference)
//
#include <hip/hip_runtime.h>

typedef __attribute__((ext_vector_type(8))) short short8;
typedef __attribute__((ext_vector_type(4))) short short4v;
typedef __attribute__((ext_vector_type(4))) float f32x4;
typedef __attribute__((ext_vector_type(16))) float f32x16;
typedef __attribute__((ext_vector_type(4))) unsigned int u32x4;
typedef __attribute__((ext_vector_type(2))) unsigned int u32x2;
typedef unsigned int u32;

#define D_MODEL 1024
#define HEADS 16
#define KD 64
#define SEQ 2048
#define BATCH 4
#define NTOK (BATCH*SEQ)    /* 8192 */
#define QKV_N (3*D_MODEL)   /* 3072 */

__device__ inline float bf2f(unsigned short u) {
    unsigned x = ((unsigned)u) << 16;
    return __builtin_bit_cast(float, x);
}
__device__ inline unsigned short f2bf(float f) {
    unsigned u = __builtin_bit_cast(unsigned, f);
    u += 0x7FFFu + ((u >> 16) & 1u);
    return (unsigned short)(u >> 16);
}
__device__ __forceinline__ void gload_lds16(const unsigned short* g, unsigned short* l) {
    __builtin_amdgcn_global_load_lds(
        (const __attribute__((address_space(1))) void*)g,
        (__attribute__((address_space(3))) void*)l, 16, 0, 0);
}
__device__ __forceinline__ u32 cvtpk(float lo, float hi) {
    u32 r; asm("v_cvt_pk_bf16_f32 %0, %1, %2" : "=v"(r) : "v"(lo), "v"(hi)); return r;
}
// Half-exchange across the lane<32 / lane>=32 split.
__device__ __forceinline__ void pl32swap(u32& a, u32& b) {
#if __has_builtin(__builtin_amdgcn_permlane32_swap)
    u32x2 r = __builtin_amdgcn_permlane32_swap(a, b, 0, 0);
    a = r[0]; b = r[1];
#else
    u32 pa = (u32)__shfl_xor((int)a, 32, 64);
    u32 pb = (u32)__shfl_xor((int)b, 32, 64);
    bool hb = (threadIdx.x & 32) != 0;
    u32 na = hb ? pb : a;
    u32 nb = hb ? b : pa;
    a = na; b = nb;
#endif
}
// Order-robust reductions: correct for any half-exchange return convention.
__device__ __forceinline__ float pairmax(float x) {
    u32 a = __builtin_bit_cast(u32, x), b = a;
    pl32swap(a, b);
    return fmaxf(x, fmaxf(__builtin_bit_cast(float, a), __builtin_bit_cast(float, b)));
}
__device__ __forceinline__ float pairsum(float x) {
    u32 a = __builtin_bit_cast(u32, x), b = a;
    pl32swap(a, b);
    return __builtin_bit_cast(float, a) + __builtin_bit_cast(float, b);
}

#define SCALE2f (0.125f * 1.44269504088896f)
#define THR_RAWf 44.36f

// ---------------------------------------------------------------------------
// attn helpers (all fully inlined, static indexing only)
// ---------------------------------------------------------------------------
__device__ __forceinline__ void qk_tile(
    const unsigned short* __restrict__ Klb, const short8 (&qf)[4],
    int l31, int hi, int ksw, f32x16& sa, f32x16& sb)
{
    #pragma unroll
    for (int r = 0; r < 16; ++r) { sa[r] = 0.f; sb[r] = 0.f; }
    __builtin_amdgcn_s_setprio(1);
    #pragma unroll
    for (int ks = 0; ks < 4; ++ks) {
        short8 kf = *reinterpret_cast<const short8*>(
            &Klb[l31*64 + ((2*ks + hi) ^ ksw)*8]);
        sa = __builtin_amdgcn_mfma_f32_32x32x16_bf16(kf, qf[ks], sa, 0, 0, 0);
    }
    #pragma unroll
    for (int ks = 0; ks < 4; ++ks) {
        short8 kf = *reinterpret_cast<const short8*>(
            &Klb[(32 + l31)*64 + ((2*ks + hi) ^ ksw)*8]);
        sb = __builtin_amdgcn_mfma_f32_32x32x16_bf16(kf, qf[ks], sb, 0, 0, 0);
    }
    __builtin_amdgcn_s_setprio(0);
}

template<bool MASK>
__device__ __forceinline__ void sm_tile(
    f32x16& sa, f32x16& sb, int d0, int l31, int hi,
    float& m, float& msc, float& sr, f32x16& o0, f32x16& o1,
    u32 (&WA)[8], u32 (&WB)[8])
{
    if (MASK && d0 <= 32) {
        const int kqA = l31 + d0      - 4*hi;
        const int kqB = l31 + d0 - 32 - 4*hi;
        #pragma unroll
        for (int r = 0; r < 16; ++r) {
            const int cr = (r & 3) + 8*(r >> 2);
            if (d0 == 0) sa[r] = (cr <= kqA) ? sa[r] : -1e30f;
            sb[r] = (cr <= kqB) ? sb[r] : -1e30f;
        }
    }
    float x[8];
    #pragma unroll
    for (int i = 0; i < 8; ++i)
        x[i] = fmaxf(fmaxf(sa[2*i], sa[2*i+1]), fmaxf(sb[2*i], sb[2*i+1]));
    float pm = fmaxf(fmaxf(fmaxf(x[0], x[1]), fmaxf(x[2], x[3])),
                     fmaxf(fmaxf(x[4], x[5]), fmaxf(x[6], x[7])));
    pm = pairmax(pm);
    if (!__all(pm <= m + THR_RAWf)) {
        float mn  = fmaxf(m, pm);
        float fac = exp2f((m - mn) * SCALE2f);
        sr *= fac;
        #pragma unroll
        for (int r = 0; r < 16; ++r) { o0[r] *= fac; o1[r] *= fac; }
        m = mn; msc = m * SCALE2f;
    }
    #pragma unroll
    for (int r = 0; r < 16; ++r) {
        sa[r] = exp2f(sa[r]*SCALE2f - msc);
        sb[r] = exp2f(sb[r]*SCALE2f - msc);
    }
    float u[8];
    #pragma unroll
    for (int i = 0; i < 8; ++i)
        u[i] = (sa[2*i] + sa[2*i+1]) + (sb[2*i] + sb[2*i+1]);
    float ts = ((u[0]+u[1]) + (u[2]+u[3])) + ((u[4]+u[5]) + (u[6]+u[7]));
    sr += pairsum(ts);
    #pragma unroll
    for (int wi = 0; wi < 8; ++wi) {
        WA[wi] = cvtpk(sa[2*wi], sa[2*wi+1]);
        WB[wi] = cvtpk(sb[2*wi], sb[2*wi+1]);
    }
}

__device__ __forceinline__ void pv_tile(
    const unsigned short* __restrict__ Vlb, const u32 (&WA)[8], const u32 (&WB)[8],
    int l31, int hi, int ksw, f32x16& o0, f32x16& o1)
{
    #pragma unroll
    for (int h32 = 0; h32 < 2; ++h32) {
        #pragma unroll
        for (int ks = 0; ks < 2; ++ks) {
            u32 W0 = h32 ? WB[4*ks+0] : WA[4*ks+0];
            u32 W1 = h32 ? WB[4*ks+1] : WA[4*ks+1];
            u32 W2 = h32 ? WB[4*ks+2] : WA[4*ks+2];
            u32 W3 = h32 ? WB[4*ks+3] : WA[4*ks+3];
            u32 s0 = hi ? W0 : W2;
            u32 s1 = hi ? W1 : W3;
            u32 r0 = (u32)__shfl_xor((int)s0, 32, 64);
            u32 r1 = (u32)__shfl_xor((int)s1, 32, 64);
            u32x4 wv;
            wv[0] = hi ? r0 : W0;
            wv[1] = hi ? r1 : W1;
            wv[2] = hi ? W2 : r0;
            wv[3] = hi ? W3 : r1;
            short8 pfrag = __builtin_bit_cast(short8, wv);
            __builtin_amdgcn_s_setprio(1);
            #pragma unroll
            for (int dt = 0; dt < 2; ++dt) {
                short8 vf = *reinterpret_cast<const short8*>(
                    &Vlb[(dt*32 + l31)*64 + ((4*h32 + 2*ks + hi) ^ ksw)*8]);
                if (dt == 0)
                    o0 = __builtin_amdgcn_mfma_f32_32x32x16_bf16(vf, pfrag, o0, 0, 0, 0);
                else
                    o1 = __builtin_amdgcn_mfma_f32_32x32x16_bf16(vf, pfrag, o1, 0, 0, 0);
            }
            __builtin_amdgcn_s_setprio(0);
        }
    }
}

// ---------------------------------------------------------------------------
// x (f32) -> bf16, elementwise, 8 per thread
// ---------------------------------------------------------------------------
__global__ __launch_bounds__(256) void cvt_kernel(
    const float* __restrict__ x, unsigned short* __restrict__ y)
{
    size_t i = (size_t)blockIdx.x * 256 + threadIdx.x;
    f32x4 a = *reinterpret_cast<const f32x4*>(x + i*8);
    f32x4 b = *reinterpret_cast<const f32x4*>(x + i*8 + 4);
    short8 o;
    #pragma unroll
    for (int j = 0; j < 4; ++j) { o[j] = (short)f2bf(a[j]); o[j+4] = (short)f2bf(b[j]); }
    *reinterpret_cast<short8*>(y + i*8) = o;
}

// ---------------------------------------------------------------------------
// WT[n][k] = bf16(W[k][n]); tile 64x64 via LDS
// ---------------------------------------------------------------------------
__global__ __launch_bounds__(256) void transpose_kernel(
    const float* __restrict__ W, unsigned short* __restrict__ WT, int K, int N)
{
    __shared__ unsigned short T[64][80];
    const int tid = threadIdx.x;
    const int n0 = blockIdx.x * 64, k0 = blockIdx.y * 64;

    int r  = tid >> 2;
    int cq = tid & 3;
    const float* src = W + (size_t)(k0 + r) * N + n0 + cq*16;
    #pragma unroll
    for (int q = 0; q < 4; ++q) {
        f32x4 v = *reinterpret_cast<const f32x4*>(src + q*4);
        #pragma unroll
        for (int j = 0; j < 4; ++j) T[cq*16 + q*4 + j][r] = f2bf(v[j]);
    }
    __syncthreads();
    int c  = tid >> 2;
    int rq = tid & 3;
    short8 o0 = *reinterpret_cast<const short8*>(&T[c][rq*16]);
    short8 o1 = *reinterpret_cast<const short8*>(&T[c][rq*16 + 8]);
    unsigned short* dst = WT + (size_t)(n0 + c) * K + k0 + rq*16;
    *reinterpret_cast<short8*>(dst)     = o0;
    *reinterpret_cast<short8*>(dst + 8) = o1;
}

// ---------------------------------------------------------------------------
// Y = A[M,K](bf16) @ BT[N,K]^T(bf16) + bias(f32).  128x128 tile, BK=64,
// 4 waves (2x2), double-buffered global_load_lds (1 barrier/K-tile),
// pre-swizzled source + swizzled ds_read. XCD-aware block swizzle.
// FUSE: also write vtg[b][h][d][s] (bf16 V^T) and f32 present k/v slices.
// ---------------------------------------------------------------------------
template<int Y_F32, int FUSE>
__global__ __launch_bounds__(256) void gemm_bt_kernel(
    const unsigned short* __restrict__ A, const unsigned short* __restrict__ BT,
    const float* __restrict__ bias, void* __restrict__ Yv,
    unsigned short* __restrict__ vtg, float* __restrict__ pres,
    int M, int N, int K)
{
    __shared__ unsigned short sA[2][128*64];
    __shared__ unsigned short sB[2][128*64];

    const int tid = threadIdx.x, lane = tid & 63, w = tid >> 6;
    const int l15 = lane & 15, lg = lane >> 4;

    const int nwg = gridDim.x * gridDim.y;
    const int bid = blockIdx.y * gridDim.x + blockIdx.x;
    const int swz = (bid & 7) * (nwg >> 3) + (bid >> 3);
    const int n0 = (swz % gridDim.x) * 128;
    const int m0 = (swz / gridDim.x) * 128;

    const int wr = w >> 1, wc = w & 1;

    f32x4 acc[4][4];
    #pragma unroll
    for (int m = 0; m < 4; ++m)
        #pragma unroll
        for (int n = 0; n < 4; ++n) acc[m][n] = f32x4{0,0,0,0};

    const int ldrow = (lane >> 3);
    const int slot  = lane & 7;
    const int nkt = K >> 6;

    #pragma unroll
    for (int i = 0; i < 4; ++i) {
        int kb  = w*4 + i;
        int row = kb*8 + ldrow;
        int sc  = slot ^ (row & 7);
        gload_lds16(&A [(size_t)(m0 + row) * K + sc*8], &sA[0][kb*512]);
        gload_lds16(&BT[(size_t)(n0 + row) * K + sc*8], &sB[0][kb*512]);
    }
    __syncthreads();

    for (int kt = 0; kt < nkt; ++kt) {
        const int buf = kt & 1;

        if (kt + 1 < nkt) {
            const int k1 = (kt + 1) << 6;
            #pragma unroll
            for (int i = 0; i < 4; ++i) {
                int kb  = w*4 + i;
                int row = kb*8 + ldrow;
                int sc  = slot ^ (row & 7);
                gload_lds16(&A [(size_t)(m0 + row) * K + k1 + sc*8], &sA[buf^1][kb*512]);
                gload_lds16(&BT[(size_t)(n0 + row) * K + k1 + sc*8], &sB[buf^1][kb*512]);
            }
        }

        #pragma unroll
        for (int kk = 0; kk < 2; ++kk) {
            short8 af[4], bfr[4];
            #pragma unroll
            for (int m = 0; m < 4; ++m) {
                int row = wr*64 + m*16 + l15;
                int ch  = (4*kk + lg) ^ (row & 7);
                af[m] = *reinterpret_cast<const short8*>(&sA[buf][row*64 + ch*8]);
            }
            #pragma unroll
            for (int n = 0; n < 4; ++n) {
                int row = wc*64 + n*16 + l15;
                int ch  = (4*kk + lg) ^ (row & 7);
                bfr[n] = *reinterpret_cast<const short8*>(&sB[buf][row*64 + ch*8]);
            }
            __builtin_amdgcn_s_setprio(1);
            #pragma unroll
            for (int m = 0; m < 4; ++m)
                #pragma unroll
                for (int n = 0; n < 4; ++n)
                    acc[m][n] = __builtin_amdgcn_mfma_f32_16x16x32_bf16(
                        af[m], bfr[n], acc[m][n], 0, 0, 0);
            __builtin_amdgcn_s_setprio(0);
        }
        __syncthreads();
    }

    #pragma unroll
    for (int n = 0; n < 4; ++n) {
        int col = n0 + wc*64 + n*16 + l15;
        float bv = bias[col];
        #pragma unroll
        for (int m = 0; m < 4; ++m) {
            int row0 = m0 + wr*64 + m*16 + lg*4;
            float v0 = acc[m][n][0] + bv;
            float v1 = acc[m][n][1] + bv;
            float v2 = acc[m][n][2] + bv;
            float v3 = acc[m][n][3] + bv;
            if (Y_F32) {
                float* Y = (float*)Yv;
                Y[(size_t)(row0+0) * N + col] = v0;
                Y[(size_t)(row0+1) * N + col] = v1;
                Y[(size_t)(row0+2) * N + col] = v2;
                Y[(size_t)(row0+3) * N + col] = v3;
            } else {
                unsigned short* Y = (unsigned short*)Yv;
                Y[(size_t)(row0+0) * N + col] = f2bf(v0);
                Y[(size_t)(row0+1) * N + col] = f2bf(v1);
                Y[(size_t)(row0+2) * N + col] = f2bf(v2);
                Y[(size_t)(row0+3) * N + col] = f2bf(v3);
            }
            if (FUSE && n0 < D_MODEL) {
                int hh = col >> 6, dd = col & 63;
                int bb = row0 >> 11, ss = row0 & (SEQ - 1);
                short4v pk;
                pk[0] = (short)f2bf(v0); pk[1] = (short)f2bf(v1);
                pk[2] = (short)f2bf(v2); pk[3] = (short)f2bf(v3);
                *reinterpret_cast<short4v*>(
                    vtg + (((size_t)bb*HEADS + hh)*KD + dd)*SEQ + ss) = pk;
                float* pv = pres + (size_t)BATCH*HEADS*SEQ*KD
                          + (((size_t)bb*HEADS + hh)*SEQ + ss)*KD + dd;
                pv[0] = v0; pv[KD] = v1; pv[2*KD] = v2; pv[3*KD] = v3;
            }
            if (FUSE && n0 >= 2*D_MODEL) {
                int rel = col - 2*D_MODEL;
                int hh = rel >> 6, dd = rel & 63;
                int bb = row0 >> 11, ss = row0 & (SEQ - 1);
                float* pk2 = pres + (((size_t)bb*HEADS + hh)*SEQ + ss)*KD + dd;
                pk2[0] = v0; pk2[KD] = v1; pk2[2*KD] = v2; pk2[3*KD] = v3;
            }
        }
    }
}

// ---------------------------------------------------------------------------
// Flash attention, swapped-operand 32x32 MFMA.
// Dual q-tile per block with SHARED K/V staging: block = (pair p, h, b)
// handles q-tiles A=p and B=15-p. Both scan keys from 0, so one staged
// 64-key tile feeds both; per-iter the wave interleaves QK_A,QK_B,
// softmax_A,softmax_B,PV_A,PV_B (two independent chains fill stalls).
// When A is active, B is >=128 keys past its diagonal -> no mask for B.
// 512 blocks, biggest pair (p=0: 32 iters) first; XCD-grouped (bid&63=(b,h)).
// ---------------------------------------------------------------------------
__global__ __launch_bounds__(256) void attn_kernel(
    const unsigned short* __restrict__ qkv,
    const unsigned short* __restrict__ vtg,
    unsigned short* __restrict__ aout)
{
    __shared__ unsigned short Kl[2][64*64];   // [key][d-chunk swz]
    __shared__ unsigned short Vl[2][64*64];   // [d][key-chunk swz]

    const int tid  = threadIdx.x;
    const int lane = tid & 63;
    const int w    = tid >> 6;
    const int l31  = lane & 31, hi = lane >> 5;

    const int bid = blockIdx.x;        // 0..511
    const int hb  = bid & 63;          // (b,h): xcd = hb & 7
    const int p   = bid >> 6;          // 0..7 ; pair (p, 15-p); p=0 first (32 iters)
    const int h = hb & 15, b = hb >> 4;

    const unsigned short* base  = qkv + (size_t)b * SEQ * QKV_N;
    const unsigned short* vbase = vtg + ((size_t)b * HEADS + h) * KD * SEQ;
    const int qoff = D_MODEL + h*KD;
    const int koff = 2*D_MODEL + h*KD;

    const int ldrow = lane >> 3;
    const int slot  = lane & 7;
    const int ksw   = l31 & 7;

    const int qbA = p, qbB = 15 - p;
    const int qminwA = qbA*128 + w*32;
    const int qminwB = qbB*128 + w*32;
    const int qrowA  = qminwA + l31;
    const int qrowB  = qminwB + l31;

    short8 qfA[4], qfB[4];
    #pragma unroll
    for (int ks = 0; ks < 4; ++ks) {
        qfA[ks] = *reinterpret_cast<const short8*>(
            base + (size_t)qrowA * QKV_N + qoff + ks*16 + hi*8);
        qfB[ks] = *reinterpret_cast<const short8*>(
            base + (size_t)qrowB * QKV_N + qoff + ks*16 + hi*8);
    }

    f32x16 o0A, o1A, o0B, o1B;
    #pragma unroll
    for (int r = 0; r < 16; ++r) { o0A[r]=0.f; o1A[r]=0.f; o0B[r]=0.f; o1B[r]=0.f; }
    float mA = -1e30f, mscA = -1e30f * SCALE2f, srA = 0.f;
    float mB = -1e30f, mscB = -1e30f * SCALE2f, srB = 0.f;

    const int nt = 2*qbB + 2;    // = 32 - 2p (covers B's full causal range)

    // prologue: stage tile 0
    #pragma unroll
    for (int i = 0; i < 2; ++i) {
        int kb = w*2 + i, row = kb*8 + ldrow, sc = slot ^ (row & 7);
        gload_lds16(&base[(size_t)row * QKV_N + koff + sc*8], &Kl[0][kb*512]);
        gload_lds16(&vbase[(size_t)row * SEQ + sc*8],         &Vl[0][kb*512]);
    }
    __syncthreads();

    for (int t = 0; t < nt; ++t) {
        const int buf = t & 1;

        if (t + 1 < nt) {   // prefetch next tile (async over compute)
            #pragma unroll
            for (int i = 0; i < 2; ++i) {
                int kb = w*2 + i, row = kb*8 + ldrow, sc = slot ^ (row & 7);
                gload_lds16(&base[(size_t)((t+1)*64 + row) * QKV_N + koff + sc*8],
                            &Kl[buf^1][kb*512]);
                gload_lds16(&vbase[(size_t)row * SEQ + (t+1)*64 + sc*8],
                            &Vl[buf^1][kb*512]);
            }
        }

        const int d0A = qminwA - t*64;
        const int d0B = qminwB - t*64;

        if (d0A > -32) {
            // Dual path: A near/at diagonal, B far past (d0B >= d0A+128, unmasked)
            f32x16 saA, sbA, saB, sbB;
            qk_tile(Kl[buf], qfA, l31, hi, ksw, saA, sbA);
            qk_tile(Kl[buf], qfB, l31, hi, ksw, saB, sbB);
            u32 WAA[8], WBA[8], WAB[8], WBB[8];
            sm_tile<true >(saA, sbA, d0A, l31, hi, mA, mscA, srA, o0A, o1A, WAA, WBA);
            sm_tile<false>(saB, sbB, 0,   l31, hi, mB, mscB, srB, o0B, o1B, WAB, WBB);
            pv_tile(Vl[buf], WAA, WBA, l31, hi, ksw, o0A, o1A);
            pv_tile(Vl[buf], WAB, WBB, l31, hi, ksw, o0B, o1B);
        } else if (d0B > -32) {
            f32x16 saB, sbB;
            qk_tile(Kl[buf], qfB, l31, hi, ksw, saB, sbB);
            u32 WAB[8], WBB[8];
            sm_tile<true >(saB, sbB, d0B, l31, hi, mB, mscB, srB, o0B, o1B, WAB, WBB);
            pv_tile(Vl[buf], WAB, WBB, l31, hi, ksw, o0B, o1B);
        }
        __syncthreads();
    }

    // ---- epilogues ----
    {
        const float inv = 1.0f / srA;
        unsigned short* orow = aout + ((size_t)b * SEQ + qrowA) * D_MODEL + h*KD;
        #pragma unroll
        for (int dt = 0; dt < 2; ++dt) {
            #pragma unroll
            for (int g = 0; g < 4; ++g) {
                short4v pk;
                #pragma unroll
                for (int j = 0; j < 4; ++j) {
                    float v = (dt == 0 ? o0A[4*g + j] : o1A[4*g + j]) * inv;
                    pk[j] = (short)f2bf(v);
                }
                *reinterpret_cast<short4v*>(orow + dt*32 + 8*g + 4*hi) = pk;
            }
        }
    }
    {
        const float inv = 1.0f / srB;
        unsigned short* orow = aout + ((size_t)b * SEQ + qrowB) * D_MODEL + h*KD;
        #pragma unroll
        for (int dt = 0; dt < 2; ++dt) {
            #pragma unroll
            for (int g = 0; g < 4; ++g) {
                short4v pk;
                #pragma unroll
                for (int j = 0; j < 4; ++j) {
                    float v = (dt == 0 ? o0B[4*g + j] : o1B[4*g + j]) * inv;
                    pk[j] = (short)f2bf(v);
                }
                *reinterpret_cast<short4v*>(orow + dt*32 + 8*g + 4*hi) = pk;
            }
        }
    }
}

// ---------------------------------------------------------------------------
extern "C" void kernel_launch(void* const* d_in, const int* in_sizes, int n_in,
                              void* d_out, int out_size, void* d_ws, size_t ws_size,
                              hipStream_t stream)
{
    const float* x      = (const float*)d_in[0];
    const float* W_attn = (const float*)d_in[1];
    const float* b_attn = (const float*)d_in[2];
    const float* W_proj = (const float*)d_in[3];
    const float* b_proj = (const float*)d_in[4];
    float* out = (float*)d_out;

    unsigned short* qkv  = (unsigned short*)d_ws;                  // [8192][3072]
    unsigned short* xbf  = qkv + (size_t)NTOK * QKV_N;             // [8192][1024] (= aout later)
    unsigned short* aout = xbf;
    unsigned short* WT   = xbf + (size_t)NTOK * D_MODEL;           // [3072][1024]
    unsigned short* WpT  = WT + (size_t)QKV_N * D_MODEL;           // [1024][1024]
    unsigned short* vtg  = WpT + (size_t)D_MODEL * D_MODEL;        // [4][16][64][2048]
    float* pres = out + (size_t)NTOK * D_MODEL;                    // [2,4,16,2048,64] f32

    cvt_kernel<<<(NTOK * D_MODEL / 8) / 256, 256, 0, stream>>>(x, xbf);
    dim3 gt1(QKV_N / 64, D_MODEL / 64);
    transpose_kernel<<<gt1, 256, 0, stream>>>(W_attn, WT, D_MODEL, QKV_N);
    dim3 gt2(D_MODEL / 64, D_MODEL / 64);
    transpose_kernel<<<gt2, 256, 0, stream>>>(W_proj, WpT, D_MODEL, D_MODEL);

    // qkv = x @ W_attn + b_attn  (+ fused V^T copy and f32 present k/v)
    dim3 g1(QKV_N / 128, NTOK / 128);
    gemm_bt_kernel<0, 1><<<g1, 256, 0, stream>>>(xbf, WT, b_attn, qkv, vtg, pres,
                                                 NTOK, QKV_N, D_MODEL);

    // causal attention (dual q-tile, shared staging, XCD-grouped)
    attn_kernel<<<512, 256, 0, stream>>>(qkv, vtg, aout);

    // out = aout @ W_proj + b_proj
    dim3 g2(D_MODEL / 128, NTOK / 128);
    gemm_bt_kernel<1, 0><<<g2, 256, 0, stream>>>(aout, WpT, b_proj, out,
                                                 nullptr, nullptr,
                                                 NTOK, D_MODEL, D_MODEL);
}

// Round 12
// 224.982 us; speedup vs baseline: 1.1376x; 1.1376x over previous
//
#include <hip/hip_runtime.h>

typedef __attribute__((ext_vector_type(8))) short short8;
typedef __attribute__((ext_vector_type(4))) short short4v;
typedef __attribute__((ext_vector_type(4))) float f32x4;
typedef __attribute__((ext_vector_type(16))) float f32x16;
typedef __attribute__((ext_vector_type(4))) unsigned int u32x4;
typedef __attribute__((ext_vector_type(2))) unsigned int u32x2;
typedef unsigned int u32;

#define D_MODEL 1024
#define HEADS 16
#define KD 64
#define SEQ 2048
#define BATCH 4
#define NTOK (BATCH*SEQ)    /* 8192 */
#define QKV_N (3*D_MODEL)   /* 3072 */

__device__ inline float bf2f(unsigned short u) {
    unsigned x = ((unsigned)u) << 16;
    return __builtin_bit_cast(float, x);
}
__device__ inline unsigned short f2bf(float f) {
    unsigned u = __builtin_bit_cast(unsigned, f);
    u += 0x7FFFu + ((u >> 16) & 1u);
    return (unsigned short)(u >> 16);
}
__device__ __forceinline__ void gload_lds16(const unsigned short* g, unsigned short* l) {
    __builtin_amdgcn_global_load_lds(
        (const __attribute__((address_space(1))) void*)g,
        (__attribute__((address_space(3))) void*)l, 16, 0, 0);
}
__device__ __forceinline__ u32 cvtpk(float lo, float hi) {
    u32 r; asm("v_cvt_pk_bf16_f32 %0, %1, %2" : "=v"(r) : "v"(lo), "v"(hi)); return r;
}
// Half-exchange across the lane<32 / lane>=32 split.
__device__ __forceinline__ void pl32swap(u32& a, u32& b) {
#if __has_builtin(__builtin_amdgcn_permlane32_swap)
    u32x2 r = __builtin_amdgcn_permlane32_swap(a, b, 0, 0);
    a = r[0]; b = r[1];
#else
    u32 pa = (u32)__shfl_xor((int)a, 32, 64);
    u32 pb = (u32)__shfl_xor((int)b, 32, 64);
    bool hb = (threadIdx.x & 32) != 0;
    u32 na = hb ? pb : a;
    u32 nb = hb ? b : pa;
    a = na; b = nb;
#endif
}
// Order-robust reductions: correct for any half-exchange return convention.
__device__ __forceinline__ float pairmax(float x) {
    u32 a = __builtin_bit_cast(u32, x), b = a;
    pl32swap(a, b);
    return fmaxf(x, fmaxf(__builtin_bit_cast(float, a), __builtin_bit_cast(float, b)));
}
__device__ __forceinline__ float pairsum(float x) {
    u32 a = __builtin_bit_cast(u32, x), b = a;
    pl32swap(a, b);
    return __builtin_bit_cast(float, a) + __builtin_bit_cast(float, b);
}

// ---------------------------------------------------------------------------
// x (f32) -> bf16, elementwise, 8 per thread
// ---------------------------------------------------------------------------
__global__ __launch_bounds__(256) void cvt_kernel(
    const float* __restrict__ x, unsigned short* __restrict__ y)
{
    size_t i = (size_t)blockIdx.x * 256 + threadIdx.x;
    f32x4 a = *reinterpret_cast<const f32x4*>(x + i*8);
    f32x4 b = *reinterpret_cast<const f32x4*>(x + i*8 + 4);
    short8 o;
    #pragma unroll
    for (int j = 0; j < 4; ++j) { o[j] = (short)f2bf(a[j]); o[j+4] = (short)f2bf(b[j]); }
    *reinterpret_cast<short8*>(y + i*8) = o;
}

// ---------------------------------------------------------------------------
// WT[n][k] = bf16(W[k][n]); tile 64x64 via LDS
// ---------------------------------------------------------------------------
__global__ __launch_bounds__(256) void transpose_kernel(
    const float* __restrict__ W, unsigned short* __restrict__ WT, int K, int N)
{
    __shared__ unsigned short T[64][80];
    const int tid = threadIdx.x;
    const int n0 = blockIdx.x * 64, k0 = blockIdx.y * 64;

    int r  = tid >> 2;
    int cq = tid & 3;
    const float* src = W + (size_t)(k0 + r) * N + n0 + cq*16;
    #pragma unroll
    for (int q = 0; q < 4; ++q) {
        f32x4 v = *reinterpret_cast<const f32x4*>(src + q*4);
        #pragma unroll
        for (int j = 0; j < 4; ++j) T[cq*16 + q*4 + j][r] = f2bf(v[j]);
    }
    __syncthreads();
    int c  = tid >> 2;
    int rq = tid & 3;
    short8 o0 = *reinterpret_cast<const short8*>(&T[c][rq*16]);
    short8 o1 = *reinterpret_cast<const short8*>(&T[c][rq*16 + 8]);
    unsigned short* dst = WT + (size_t)(n0 + c) * K + k0 + rq*16;
    *reinterpret_cast<short8*>(dst)     = o0;
    *reinterpret_cast<short8*>(dst + 8) = o1;
}

// ---------------------------------------------------------------------------
// Y = A[M,K](bf16) @ BT[N,K]^T(bf16) + bias(f32).  128x128 tile, BK=32,
// double-buffered global_load_lds (1 barrier/K-tile, 32KB LDS -> ~5 blk/CU),
// pre-swizzled source + swizzled ds_read. XCD-aware block swizzle.
// FUSE: also write vtg[b][h][d][s] (bf16 V^T) and f32 present k/v slices.
// ---------------------------------------------------------------------------
template<int Y_F32, int FUSE>
__global__ __launch_bounds__(256) void gemm_bt_kernel(
    const unsigned short* __restrict__ A, const unsigned short* __restrict__ BT,
    const float* __restrict__ bias, void* __restrict__ Yv,
    unsigned short* __restrict__ vtg, float* __restrict__ pres,
    int M, int N, int K)
{
    __shared__ unsigned short sA[2][128*32];
    __shared__ unsigned short sB[2][128*32];

    const int tid = threadIdx.x, lane = tid & 63, w = tid >> 6;
    const int l15 = lane & 15, lg = lane >> 4;

    const int nwg = gridDim.x * gridDim.y;
    const int bid = blockIdx.y * gridDim.x + blockIdx.x;
    const int swz = (bid & 7) * (nwg >> 3) + (bid >> 3);
    const int n0 = (swz % gridDim.x) * 128;
    const int m0 = (swz / gridDim.x) * 128;

    const int wr = w >> 1, wc = w & 1;

    f32x4 acc[4][4];
    #pragma unroll
    for (int m = 0; m < 4; ++m)
        #pragma unroll
        for (int n = 0; n < 4; ++n) acc[m][n] = f32x4{0,0,0,0};

    const int nkt = K >> 5;

    // staging geometry: slot = i*256 + tid; row = slot>>2; c = slot&3
    // source chunk sc = c ^ (row&3)  (inverse swizzle); LDS dest linear slot*8
    #pragma unroll
    for (int i = 0; i < 2; ++i) {
        int slot = i*256 + tid;
        int row = slot >> 2, c = slot & 3;
        int sc = c ^ (row & 3);
        gload_lds16(&A [(size_t)(m0 + row) * K + sc*8], &sA[0][slot*8]);
        gload_lds16(&BT[(size_t)(n0 + row) * K + sc*8], &sB[0][slot*8]);
    }
    __syncthreads();

    for (int kt = 0; kt < nkt; ++kt) {
        const int buf = kt & 1;

        if (kt + 1 < nkt) {   // prefetch next k-tile (async over compute)
            const int k1 = (kt + 1) << 5;
            #pragma unroll
            for (int i = 0; i < 2; ++i) {
                int slot = i*256 + tid;
                int row = slot >> 2, c = slot & 3;
                int sc = c ^ (row & 3);
                gload_lds16(&A [(size_t)(m0 + row) * K + k1 + sc*8], &sA[buf^1][slot*8]);
                gload_lds16(&BT[(size_t)(n0 + row) * K + k1 + sc*8], &sB[buf^1][slot*8]);
            }
        }

        short8 af[4], bfr[4];
        #pragma unroll
        for (int m = 0; m < 4; ++m) {
            int row = wr*64 + m*16 + l15;
            int ch  = lg ^ (row & 3);
            af[m] = *reinterpret_cast<const short8*>(&sA[buf][row*32 + ch*8]);
        }
        #pragma unroll
        for (int n = 0; n < 4; ++n) {
            int row = wc*64 + n*16 + l15;
            int ch  = lg ^ (row & 3);
            bfr[n] = *reinterpret_cast<const short8*>(&sB[buf][row*32 + ch*8]);
        }
        __builtin_amdgcn_s_setprio(1);
        #pragma unroll
        for (int m = 0; m < 4; ++m)
            #pragma unroll
            for (int n = 0; n < 4; ++n)
                acc[m][n] = __builtin_amdgcn_mfma_f32_16x16x32_bf16(
                    af[m], bfr[n], acc[m][n], 0, 0, 0);
        __builtin_amdgcn_s_setprio(0);
        __syncthreads();   // drains prefetch; protects buf for overwrite next iter
    }

    #pragma unroll
    for (int n = 0; n < 4; ++n) {
        int col = n0 + wc*64 + n*16 + l15;
        float bv = bias[col];
        #pragma unroll
        for (int m = 0; m < 4; ++m) {
            int row0 = m0 + wr*64 + m*16 + lg*4;
            float v0 = acc[m][n][0] + bv;
            float v1 = acc[m][n][1] + bv;
            float v2 = acc[m][n][2] + bv;
            float v3 = acc[m][n][3] + bv;
            if (Y_F32) {
                float* Y = (float*)Yv;
                Y[(size_t)(row0+0) * N + col] = v0;
                Y[(size_t)(row0+1) * N + col] = v1;
                Y[(size_t)(row0+2) * N + col] = v2;
                Y[(size_t)(row0+3) * N + col] = v3;
            } else {
                unsigned short* Y = (unsigned short*)Yv;
                Y[(size_t)(row0+0) * N + col] = f2bf(v0);
                Y[(size_t)(row0+1) * N + col] = f2bf(v1);
                Y[(size_t)(row0+2) * N + col] = f2bf(v2);
                Y[(size_t)(row0+3) * N + col] = f2bf(v3);
            }
            if (FUSE && n0 < D_MODEL) {
                int hh = col >> 6, dd = col & 63;
                int bb = row0 >> 11, ss = row0 & (SEQ - 1);
                short4v pk;
                pk[0] = (short)f2bf(v0); pk[1] = (short)f2bf(v1);
                pk[2] = (short)f2bf(v2); pk[3] = (short)f2bf(v3);
                *reinterpret_cast<short4v*>(
                    vtg + (((size_t)bb*HEADS + hh)*KD + dd)*SEQ + ss) = pk;
                float* pv = pres + (size_t)BATCH*HEADS*SEQ*KD
                          + (((size_t)bb*HEADS + hh)*SEQ + ss)*KD + dd;
                pv[0] = v0; pv[KD] = v1; pv[2*KD] = v2; pv[3*KD] = v3;
            }
            if (FUSE && n0 >= 2*D_MODEL) {
                int rel = col - 2*D_MODEL;
                int hh = rel >> 6, dd = rel & 63;
                int bb = row0 >> 11, ss = row0 & (SEQ - 1);
                float* pk2 = pres + (((size_t)bb*HEADS + hh)*SEQ + ss)*KD + dd;
                pk2[0] = v0; pk2[KD] = v1; pk2[2*KD] = v2; pk2[3*KD] = v3;
            }
        }
    }
}

// ---------------------------------------------------------------------------
// Flash attention, swapped-operand 32x32 MFMA, merged 64-key stage.
// One 128-row q-tile per block -> 1024 blocks (4/CU resident); largest
// q-tiles dispatched first for load balance; XCD-grouped (bid&63 = (b,h)).
// [Reverted to the round-10 proven version.]
// ---------------------------------------------------------------------------
__global__ __launch_bounds__(256) void attn_kernel(
    const unsigned short* __restrict__ qkv,
    const unsigned short* __restrict__ vtg,
    unsigned short* __restrict__ aout)
{
    __shared__ unsigned short Kl[2][64*64];   // [key][d-chunk swz]
    __shared__ unsigned short Vl[2][64*64];   // [d][key-chunk swz]

    const int tid  = threadIdx.x;
    const int lane = tid & 63;
    const int w    = tid >> 6;
    const int l31  = lane & 31, hi = lane >> 5;

    const int bid = blockIdx.x;        // 0..1023
    const int hb  = bid & 63;          // (b,h): xcd = hb & 7, stable per (b,h)
    const int qb  = 15 - (bid >> 6);   // 15..0 : biggest tiles first
    const int h = hb & 15, b = hb >> 4;

    const unsigned short* base  = qkv + (size_t)b * SEQ * QKV_N;
    const unsigned short* vbase = vtg + ((size_t)b * HEADS + h) * KD * SEQ;
    const int qoff = D_MODEL + h*KD;
    const int koff = 2*D_MODEL + h*KD;

    const float SCALE2 = 0.125f * 1.44269504088896f;   // 0.18034
    const float THR_RAW = 44.36f;                      // 8 / SCALE2

    const int ldrow = lane >> 3;
    const int slot  = lane & 7;
    const int ksw   = l31 & 7;

    const int q0 = qb * 128;
    const int qrow  = q0 + w*32 + l31;
    const int qminw = q0 + w*32;

    short8 qf[4];
    #pragma unroll
    for (int ks = 0; ks < 4; ++ks)
        qf[ks] = *reinterpret_cast<const short8*>(
            base + (size_t)qrow * QKV_N + qoff + ks*16 + hi*8);

    f32x16 o0, o1;
    #pragma unroll
    for (int r = 0; r < 16; ++r) { o0[r] = 0.f; o1[r] = 0.f; }
    float m = -1e30f, msc = -1e30f * 0.180336887f, sr = 0.f;

    const int nt = 2*qb + 2;

    // prologue: stage tile 0
    #pragma unroll
    for (int i = 0; i < 2; ++i) {
        int kb = w*2 + i, row = kb*8 + ldrow, sc = slot ^ (row & 7);
        gload_lds16(&base[(size_t)row * QKV_N + koff + sc*8], &Kl[0][kb*512]);
        gload_lds16(&vbase[(size_t)row * SEQ + sc*8],         &Vl[0][kb*512]);
    }
    __syncthreads();

    for (int t = 0; t < nt; ++t) {
        const int buf = t & 1;

        if (t + 1 < nt) {   // prefetch next tile (async over compute)
            #pragma unroll
            for (int i = 0; i < 2; ++i) {
                int kb = w*2 + i, row = kb*8 + ldrow, sc = slot ^ (row & 7);
                gload_lds16(&base[(size_t)((t+1)*64 + row) * QKV_N + koff + sc*8],
                            &Kl[buf^1][kb*512]);
                gload_lds16(&vbase[(size_t)row * SEQ + (t+1)*64 + sc*8],
                            &Vl[buf^1][kb*512]);
            }
        }

        const int d0 = qminw - t*64;
        if (d0 > -32) {    // wave has work in this 64-key tile
            // ---- QK^T both 32-key halves ----
            f32x16 sa, sb;
            #pragma unroll
            for (int r = 0; r < 16; ++r) { sa[r] = 0.f; sb[r] = 0.f; }
            __builtin_amdgcn_s_setprio(1);
            #pragma unroll
            for (int ks = 0; ks < 4; ++ks) {
                short8 kf = *reinterpret_cast<const short8*>(
                    &Kl[buf][l31*64 + ((2*ks + hi) ^ ksw)*8]);
                sa = __builtin_amdgcn_mfma_f32_32x32x16_bf16(kf, qf[ks], sa, 0, 0, 0);
            }
            #pragma unroll
            for (int ks = 0; ks < 4; ++ks) {
                short8 kf = *reinterpret_cast<const short8*>(
                    &Kl[buf][(32 + l31)*64 + ((2*ks + hi) ^ ksw)*8]);
                sb = __builtin_amdgcn_mfma_f32_32x32x16_bf16(kf, qf[ks], sb, 0, 0, 0);
            }
            __builtin_amdgcn_s_setprio(0);

            // ---- causal mask (keys: A half = t*64+cr+4hi, B half = +32) ----
            if (d0 <= 32) {
                const int kqA = l31 + d0      - 4*hi;
                const int kqB = l31 + d0 - 32 - 4*hi;
                #pragma unroll
                for (int r = 0; r < 16; ++r) {
                    const int cr = (r & 3) + 8*(r >> 2);
                    if (d0 == 0) sa[r] = (cr <= kqA) ? sa[r] : -1e30f;
                    sb[r] = (cr <= kqB) ? sb[r] : -1e30f;
                }
            }

            // ---- max tree over 32 + cross-pair, defer-rescale ----
            float x[8];
            #pragma unroll
            for (int i = 0; i < 8; ++i)
                x[i] = fmaxf(fmaxf(sa[2*i], sa[2*i+1]), fmaxf(sb[2*i], sb[2*i+1]));
            float pm = fmaxf(fmaxf(fmaxf(x[0], x[1]), fmaxf(x[2], x[3])),
                             fmaxf(fmaxf(x[4], x[5]), fmaxf(x[6], x[7])));
            pm = pairmax(pm);
            if (!__all(pm <= m + THR_RAW)) {
                float mn  = fmaxf(m, pm);
                float fac = exp2f((m - mn) * SCALE2);
                sr *= fac;
                #pragma unroll
                for (int r = 0; r < 16; ++r) { o0[r] *= fac; o1[r] *= fac; }
                m = mn; msc = m * SCALE2;
            }

            // ---- exp + tree sum ----
            #pragma unroll
            for (int r = 0; r < 16; ++r) {
                sa[r] = exp2f(sa[r]*SCALE2 - msc);
                sb[r] = exp2f(sb[r]*SCALE2 - msc);
            }
            float u[8];
            #pragma unroll
            for (int i = 0; i < 8; ++i)
                u[i] = (sa[2*i] + sa[2*i+1]) + (sb[2*i] + sb[2*i+1]);
            float ts = ((u[0]+u[1]) + (u[2]+u[3])) + ((u[4]+u[5]) + (u[6]+u[7]));
            sr += pairsum(ts);

            // ---- pack P to bf16 ----
            u32 WA[8], WB[8];
            #pragma unroll
            for (int wi = 0; wi < 8; ++wi) {
                WA[wi] = cvtpk(sa[2*wi], sa[2*wi+1]);
                WB[wi] = cvtpk(sb[2*wi], sb[2*wi+1]);
            }

            // ---- PV: O^T += V^T @ P^T (proven shfl-based cross-half pack) ----
            #pragma unroll
            for (int h32 = 0; h32 < 2; ++h32) {
                #pragma unroll
                for (int ks = 0; ks < 2; ++ks) {
                    u32 W0 = h32 ? WB[4*ks+0] : WA[4*ks+0];
                    u32 W1 = h32 ? WB[4*ks+1] : WA[4*ks+1];
                    u32 W2 = h32 ? WB[4*ks+2] : WA[4*ks+2];
                    u32 W3 = h32 ? WB[4*ks+3] : WA[4*ks+3];
                    u32 s0 = hi ? W0 : W2;
                    u32 s1 = hi ? W1 : W3;
                    u32 r0 = (u32)__shfl_xor((int)s0, 32, 64);
                    u32 r1 = (u32)__shfl_xor((int)s1, 32, 64);
                    u32x4 wv;
                    wv[0] = hi ? r0 : W0;
                    wv[1] = hi ? r1 : W1;
                    wv[2] = hi ? W2 : r0;
                    wv[3] = hi ? W3 : r1;
                    short8 pfrag = __builtin_bit_cast(short8, wv);
                    __builtin_amdgcn_s_setprio(1);
                    #pragma unroll
                    for (int dt = 0; dt < 2; ++dt) {
                        short8 vf = *reinterpret_cast<const short8*>(
                            &Vl[buf][(dt*32 + l31)*64 + ((4*h32 + 2*ks + hi) ^ ksw)*8]);
                        if (dt == 0)
                            o0 = __builtin_amdgcn_mfma_f32_32x32x16_bf16(vf, pfrag, o0, 0, 0, 0);
                        else
                            o1 = __builtin_amdgcn_mfma_f32_32x32x16_bf16(vf, pfrag, o1, 0, 0, 0);
                    }
                    __builtin_amdgcn_s_setprio(0);
                }
            }
        }
        __syncthreads();
    }

    // ---- epilogue ----
    const float inv = 1.0f / sr;
    unsigned short* orow = aout + ((size_t)b * SEQ + qrow) * D_MODEL + h*KD;
    #pragma unroll
    for (int dt = 0; dt < 2; ++dt) {
        #pragma unroll
        for (int g = 0; g < 4; ++g) {
            short4v pk;
            #pragma unroll
            for (int j = 0; j < 4; ++j) {
                float v = (dt == 0 ? o0[4*g + j] : o1[4*g + j]) * inv;
                pk[j] = (short)f2bf(v);
            }
            *reinterpret_cast<short4v*>(orow + dt*32 + 8*g + 4*hi) = pk;
        }
    }
}

// ---------------------------------------------------------------------------
extern "C" void kernel_launch(void* const* d_in, const int* in_sizes, int n_in,
                              void* d_out, int out_size, void* d_ws, size_t ws_size,
                              hipStream_t stream)
{
    const float* x      = (const float*)d_in[0];
    const float* W_attn = (const float*)d_in[1];
    const float* b_attn = (const float*)d_in[2];
    const float* W_proj = (const float*)d_in[3];
    const float* b_proj = (const float*)d_in[4];
    float* out = (float*)d_out;

    unsigned short* qkv  = (unsigned short*)d_ws;                  // [8192][3072]
    unsigned short* xbf  = qkv + (size_t)NTOK * QKV_N;             // [8192][1024] (= aout later)
    unsigned short* aout = xbf;
    unsigned short* WT   = xbf + (size_t)NTOK * D_MODEL;           // [3072][1024]
    unsigned short* WpT  = WT + (size_t)QKV_N * D_MODEL;           // [1024][1024]
    unsigned short* vtg  = WpT + (size_t)D_MODEL * D_MODEL;        // [4][16][64][2048]
    float* pres = out + (size_t)NTOK * D_MODEL;                    // [2,4,16,2048,64] f32

    cvt_kernel<<<(NTOK * D_MODEL / 8) / 256, 256, 0, stream>>>(x, xbf);
    dim3 gt1(QKV_N / 64, D_MODEL / 64);
    transpose_kernel<<<gt1, 256, 0, stream>>>(W_attn, WT, D_MODEL, QKV_N);
    dim3 gt2(D_MODEL / 64, D_MODEL / 64);
    transpose_kernel<<<gt2, 256, 0, stream>>>(W_proj, WpT, D_MODEL, D_MODEL);

    // qkv = x @ W_attn + b_attn  (+ fused V^T copy and f32 present k/v)
    dim3 g1(QKV_N / 128, NTOK / 128);
    gemm_bt_kernel<0, 1><<<g1, 256, 0, stream>>>(xbf, WT, b_attn, qkv, vtg, pres,
                                                 NTOK, QKV_N, D_MODEL);

    // causal attention (1024 blocks, biggest-first, XCD-grouped)
    attn_kernel<<<1024, 256, 0, stream>>>(qkv, vtg, aout);

    // out = aout @ W_proj + b_proj
    dim3 g2(D_MODEL / 128, NTOK / 128);
    gemm_bt_kernel<1, 0><<<g2, 256, 0, stream>>>(aout, WpT, b_proj, out,
                                                 nullptr, nullptr,
                                                 NTOK, D_MODEL, D_MODEL);
}

// Round 13
// 201.756 us; speedup vs baseline: 1.2685x; 1.1151x over previous
//
#include <hip/hip_runtime.h>

typedef __attribute__((ext_vector_type(8))) short short8;
typedef __attribute__((ext_vector_type(4))) short short4v;
typedef __attribute__((ext_vector_type(4))) float f32x4;
typedef __attribute__((ext_vector_type(16))) float f32x16;
typedef __attribute__((ext_vector_type(4))) unsigned int u32x4;
typedef __attribute__((ext_vector_type(2))) unsigned int u32x2;
typedef unsigned int u32;

#define D_MODEL 1024
#define HEADS 16
#define KD 64
#define SEQ 2048
#define BATCH 4
#define NTOK (BATCH*SEQ)    /* 8192 */
#define QKV_N (3*D_MODEL)   /* 3072 */

__device__ inline float bf2f(unsigned short u) {
    unsigned x = ((unsigned)u) << 16;
    return __builtin_bit_cast(float, x);
}
__device__ inline unsigned short f2bf(float f) {
    unsigned u = __builtin_bit_cast(unsigned, f);
    u += 0x7FFFu + ((u >> 16) & 1u);
    return (unsigned short)(u >> 16);
}
__device__ __forceinline__ void gload_lds16(const unsigned short* g, unsigned short* l) {
    __builtin_amdgcn_global_load_lds(
        (const __attribute__((address_space(1))) void*)g,
        (__attribute__((address_space(3))) void*)l, 16, 0, 0);
}
__device__ __forceinline__ u32 cvtpk(float lo, float hi) {
    u32 r; asm("v_cvt_pk_bf16_f32 %0, %1, %2" : "=v"(r) : "v"(lo), "v"(hi)); return r;
}
// Half-exchange across the lane<32 / lane>=32 split.
__device__ __forceinline__ void pl32swap(u32& a, u32& b) {
#if __has_builtin(__builtin_amdgcn_permlane32_swap)
    u32x2 r = __builtin_amdgcn_permlane32_swap(a, b, 0, 0);
    a = r[0]; b = r[1];
#else
    u32 pa = (u32)__shfl_xor((int)a, 32, 64);
    u32 pb = (u32)__shfl_xor((int)b, 32, 64);
    bool hb = (threadIdx.x & 32) != 0;
    u32 na = hb ? pb : a;
    u32 nb = hb ? b : pa;
    a = na; b = nb;
#endif
}
// Order-robust reductions: correct for any half-exchange return convention.
__device__ __forceinline__ float pairmax(float x) {
    u32 a = __builtin_bit_cast(u32, x), b = a;
    pl32swap(a, b);
    return fmaxf(x, fmaxf(__builtin_bit_cast(float, a), __builtin_bit_cast(float, b)));
}
__device__ __forceinline__ float pairsum(float x) {
    u32 a = __builtin_bit_cast(u32, x), b = a;
    pl32swap(a, b);
    return __builtin_bit_cast(float, a) + __builtin_bit_cast(float, b);
}

// ---------------------------------------------------------------------------
// x (f32) -> bf16, elementwise, 8 per thread
// ---------------------------------------------------------------------------
__global__ __launch_bounds__(256) void cvt_kernel(
    const float* __restrict__ x, unsigned short* __restrict__ y)
{
    size_t i = (size_t)blockIdx.x * 256 + threadIdx.x;
    f32x4 a = *reinterpret_cast<const f32x4*>(x + i*8);
    f32x4 b = *reinterpret_cast<const f32x4*>(x + i*8 + 4);
    short8 o;
    #pragma unroll
    for (int j = 0; j < 4; ++j) { o[j] = (short)f2bf(a[j]); o[j+4] = (short)f2bf(b[j]); }
    *reinterpret_cast<short8*>(y + i*8) = o;
}

// ---------------------------------------------------------------------------
// WT[n][k] = bf16(W[k][n]); tile 64x64 via LDS
// ---------------------------------------------------------------------------
__global__ __launch_bounds__(256) void transpose_kernel(
    const float* __restrict__ W, unsigned short* __restrict__ WT, int K, int N)
{
    __shared__ unsigned short T[64][80];
    const int tid = threadIdx.x;
    const int n0 = blockIdx.x * 64, k0 = blockIdx.y * 64;

    int r  = tid >> 2;
    int cq = tid & 3;
    const float* src = W + (size_t)(k0 + r) * N + n0 + cq*16;
    #pragma unroll
    for (int q = 0; q < 4; ++q) {
        f32x4 v = *reinterpret_cast<const f32x4*>(src + q*4);
        #pragma unroll
        for (int j = 0; j < 4; ++j) T[cq*16 + q*4 + j][r] = f2bf(v[j]);
    }
    __syncthreads();
    int c  = tid >> 2;
    int rq = tid & 3;
    short8 o0 = *reinterpret_cast<const short8*>(&T[c][rq*16]);
    short8 o1 = *reinterpret_cast<const short8*>(&T[c][rq*16 + 8]);
    unsigned short* dst = WT + (size_t)(n0 + c) * K + k0 + rq*16;
    *reinterpret_cast<short8*>(dst)     = o0;
    *reinterpret_cast<short8*>(dst + 8) = o1;
}

// ---------------------------------------------------------------------------
// Y = A[M,K](bf16) @ BT[N,K]^T(bf16) + bias(f32).  128x128 tile, BK=64,
// 4 waves (2x2), double-buffered global_load_lds (1 barrier/K-tile),
// pre-swizzled source + swizzled ds_read. XCD-aware block swizzle.
// FUSE: also write vtg[b][h][d][s] (bf16 V^T) and f32 present k/v slices.
// [round-10 proven version]
// ---------------------------------------------------------------------------
template<int Y_F32, int FUSE>
__global__ __launch_bounds__(256) void gemm_bt_kernel(
    const unsigned short* __restrict__ A, const unsigned short* __restrict__ BT,
    const float* __restrict__ bias, void* __restrict__ Yv,
    unsigned short* __restrict__ vtg, float* __restrict__ pres,
    int M, int N, int K)
{
    __shared__ unsigned short sA[2][128*64];
    __shared__ unsigned short sB[2][128*64];

    const int tid = threadIdx.x, lane = tid & 63, w = tid >> 6;
    const int l15 = lane & 15, lg = lane >> 4;

    const int nwg = gridDim.x * gridDim.y;
    const int bid = blockIdx.y * gridDim.x + blockIdx.x;
    const int swz = (bid & 7) * (nwg >> 3) + (bid >> 3);
    const int n0 = (swz % gridDim.x) * 128;
    const int m0 = (swz / gridDim.x) * 128;

    const int wr = w >> 1, wc = w & 1;

    f32x4 acc[4][4];
    #pragma unroll
    for (int m = 0; m < 4; ++m)
        #pragma unroll
        for (int n = 0; n < 4; ++n) acc[m][n] = f32x4{0,0,0,0};

    const int ldrow = (lane >> 3);
    const int slot  = lane & 7;
    const int nkt = K >> 6;

    #pragma unroll
    for (int i = 0; i < 4; ++i) {
        int kb  = w*4 + i;
        int row = kb*8 + ldrow;
        int sc  = slot ^ (row & 7);
        gload_lds16(&A [(size_t)(m0 + row) * K + sc*8], &sA[0][kb*512]);
        gload_lds16(&BT[(size_t)(n0 + row) * K + sc*8], &sB[0][kb*512]);
    }
    __syncthreads();

    for (int kt = 0; kt < nkt; ++kt) {
        const int buf = kt & 1;

        if (kt + 1 < nkt) {
            const int k1 = (kt + 1) << 6;
            #pragma unroll
            for (int i = 0; i < 4; ++i) {
                int kb  = w*4 + i;
                int row = kb*8 + ldrow;
                int sc  = slot ^ (row & 7);
                gload_lds16(&A [(size_t)(m0 + row) * K + k1 + sc*8], &sA[buf^1][kb*512]);
                gload_lds16(&BT[(size_t)(n0 + row) * K + k1 + sc*8], &sB[buf^1][kb*512]);
            }
        }

        #pragma unroll
        for (int kk = 0; kk < 2; ++kk) {
            short8 af[4], bfr[4];
            #pragma unroll
            for (int m = 0; m < 4; ++m) {
                int row = wr*64 + m*16 + l15;
                int ch  = (4*kk + lg) ^ (row & 7);
                af[m] = *reinterpret_cast<const short8*>(&sA[buf][row*64 + ch*8]);
            }
            #pragma unroll
            for (int n = 0; n < 4; ++n) {
                int row = wc*64 + n*16 + l15;
                int ch  = (4*kk + lg) ^ (row & 7);
                bfr[n] = *reinterpret_cast<const short8*>(&sB[buf][row*64 + ch*8]);
            }
            __builtin_amdgcn_s_setprio(1);
            #pragma unroll
            for (int m = 0; m < 4; ++m)
                #pragma unroll
                for (int n = 0; n < 4; ++n)
                    acc[m][n] = __builtin_amdgcn_mfma_f32_16x16x32_bf16(
                        af[m], bfr[n], acc[m][n], 0, 0, 0);
            __builtin_amdgcn_s_setprio(0);
        }
        __syncthreads();
    }

    #pragma unroll
    for (int n = 0; n < 4; ++n) {
        int col = n0 + wc*64 + n*16 + l15;
        float bv = bias[col];
        #pragma unroll
        for (int m = 0; m < 4; ++m) {
            int row0 = m0 + wr*64 + m*16 + lg*4;
            float v0 = acc[m][n][0] + bv;
            float v1 = acc[m][n][1] + bv;
            float v2 = acc[m][n][2] + bv;
            float v3 = acc[m][n][3] + bv;
            if (Y_F32) {
                float* Y = (float*)Yv;
                Y[(size_t)(row0+0) * N + col] = v0;
                Y[(size_t)(row0+1) * N + col] = v1;
                Y[(size_t)(row0+2) * N + col] = v2;
                Y[(size_t)(row0+3) * N + col] = v3;
            } else {
                unsigned short* Y = (unsigned short*)Yv;
                Y[(size_t)(row0+0) * N + col] = f2bf(v0);
                Y[(size_t)(row0+1) * N + col] = f2bf(v1);
                Y[(size_t)(row0+2) * N + col] = f2bf(v2);
                Y[(size_t)(row0+3) * N + col] = f2bf(v3);
            }
            if (FUSE && n0 < D_MODEL) {
                int hh = col >> 6, dd = col & 63;
                int bb = row0 >> 11, ss = row0 & (SEQ - 1);
                short4v pk;
                pk[0] = (short)f2bf(v0); pk[1] = (short)f2bf(v1);
                pk[2] = (short)f2bf(v2); pk[3] = (short)f2bf(v3);
                *reinterpret_cast<short4v*>(
                    vtg + (((size_t)bb*HEADS + hh)*KD + dd)*SEQ + ss) = pk;
                float* pv = pres + (size_t)BATCH*HEADS*SEQ*KD
                          + (((size_t)bb*HEADS + hh)*SEQ + ss)*KD + dd;
                pv[0] = v0; pv[KD] = v1; pv[2*KD] = v2; pv[3*KD] = v3;
            }
            if (FUSE && n0 >= 2*D_MODEL) {
                int rel = col - 2*D_MODEL;
                int hh = rel >> 6, dd = rel & 63;
                int bb = row0 >> 11, ss = row0 & (SEQ - 1);
                float* pk2 = pres + (((size_t)bb*HEADS + hh)*SEQ + ss)*KD + dd;
                pk2[0] = v0; pk2[KD] = v1; pk2[2*KD] = v2; pk2[3*KD] = v3;
            }
        }
    }
}

// ---------------------------------------------------------------------------
// Flash attention, swapped-operand 32x32 MFMA, merged 64-key stage.
// WAVE-PAIRED q-tiles with shared K/V staging: 512-thread block (8 waves);
// waves 0-3 -> q-tile A=2i, waves 4-7 -> B=2i+1 (adjacent sizes). One staged
// 64-key tile serves both tiles -> per-(b,h) stage-iters 272 -> 144 (-47%).
// Per-thread state identical to the proven round-10 kernel.
// 512 blocks, biggest pair (i=7, 32 iters) first; XCD-grouped (bid&63=(b,h)).
// ---------------------------------------------------------------------------
__global__ __launch_bounds__(512) void attn_kernel(
    const unsigned short* __restrict__ qkv,
    const unsigned short* __restrict__ vtg,
    unsigned short* __restrict__ aout)
{
    __shared__ unsigned short Kl[2][64*64];   // [key][d-chunk swz]
    __shared__ unsigned short Vl[2][64*64];   // [d][key-chunk swz]

    const int tid  = threadIdx.x;
    const int lane = tid & 63;
    const int w    = tid >> 6;          // 0..7
    const int wg   = w >> 2;            // 0: tile A, 1: tile B
    const int wl   = w & 3;             // wave within tile group
    const int l31  = lane & 31, hi = lane >> 5;

    const int bid = blockIdx.x;         // 0..511
    const int hb  = bid & 63;           // (b,h): xcd = hb & 7
    const int i   = 7 - (bid >> 6);     // 7..0 : biggest pairs first
    const int qb  = 2*i + wg;           // this wave-group's q-tile
    const int h = hb & 15, b = hb >> 4;

    const unsigned short* base  = qkv + (size_t)b * SEQ * QKV_N;
    const unsigned short* vbase = vtg + ((size_t)b * HEADS + h) * KD * SEQ;
    const int qoff = D_MODEL + h*KD;
    const int koff = 2*D_MODEL + h*KD;

    const float SCALE2 = 0.125f * 1.44269504088896f;   // 0.18034
    const float THR_RAW = 44.36f;                      // 8 / SCALE2

    const int ldrow = lane >> 3;
    const int slot  = lane & 7;
    const int ksw   = l31 & 7;

    const int q0 = qb * 128;
    const int qrow  = q0 + wl*32 + l31;
    const int qminw = q0 + wl*32;

    short8 qf[4];
    #pragma unroll
    for (int ks = 0; ks < 4; ++ks)
        qf[ks] = *reinterpret_cast<const short8*>(
            base + (size_t)qrow * QKV_N + qoff + ks*16 + hi*8);

    f32x16 o0, o1;
    #pragma unroll
    for (int r = 0; r < 16; ++r) { o0[r] = 0.f; o1[r] = 0.f; }
    float m = -1e30f, msc = -1e30f * 0.180336887f, sr = 0.f;

    const int nt = 4*i + 4;             // covers B's (2i+1) causal range

    // prologue: stage tile 0 (8 waves: wave w stages rows w*8..w*8+7)
    {
        int row = w*8 + ldrow, sc = slot ^ (row & 7);
        gload_lds16(&base[(size_t)row * QKV_N + koff + sc*8], &Kl[0][w*512]);
        gload_lds16(&vbase[(size_t)row * SEQ + sc*8],         &Vl[0][w*512]);
    }
    __syncthreads();

    for (int t = 0; t < nt; ++t) {
        const int buf = t & 1;

        if (t + 1 < nt) {   // prefetch next tile (async over compute)
            int row = w*8 + ldrow, sc = slot ^ (row & 7);
            gload_lds16(&base[(size_t)((t+1)*64 + row) * QKV_N + koff + sc*8],
                        &Kl[buf^1][w*512]);
            gload_lds16(&vbase[(size_t)row * SEQ + (t+1)*64 + sc*8],
                        &Vl[buf^1][w*512]);
        }

        const int d0 = qminw - t*64;
        if (d0 > -32) {    // wave has work in this 64-key tile
            // ---- QK^T both 32-key halves ----
            f32x16 sa, sb;
            #pragma unroll
            for (int r = 0; r < 16; ++r) { sa[r] = 0.f; sb[r] = 0.f; }
            __builtin_amdgcn_s_setprio(1);
            #pragma unroll
            for (int ks = 0; ks < 4; ++ks) {
                short8 kf = *reinterpret_cast<const short8*>(
                    &Kl[buf][l31*64 + ((2*ks + hi) ^ ksw)*8]);
                sa = __builtin_amdgcn_mfma_f32_32x32x16_bf16(kf, qf[ks], sa, 0, 0, 0);
            }
            #pragma unroll
            for (int ks = 0; ks < 4; ++ks) {
                short8 kf = *reinterpret_cast<const short8*>(
                    &Kl[buf][(32 + l31)*64 + ((2*ks + hi) ^ ksw)*8]);
                sb = __builtin_amdgcn_mfma_f32_32x32x16_bf16(kf, qf[ks], sb, 0, 0, 0);
            }
            __builtin_amdgcn_s_setprio(0);

            // ---- causal mask (keys: A half = t*64+cr+4hi, B half = +32) ----
            if (d0 <= 32) {
                const int kqA = l31 + d0      - 4*hi;
                const int kqB = l31 + d0 - 32 - 4*hi;
                #pragma unroll
                for (int r = 0; r < 16; ++r) {
                    const int cr = (r & 3) + 8*(r >> 2);
                    if (d0 == 0) sa[r] = (cr <= kqA) ? sa[r] : -1e30f;
                    sb[r] = (cr <= kqB) ? sb[r] : -1e30f;
                }
            }

            // ---- max tree over 32 + cross-pair, defer-rescale ----
            float x[8];
            #pragma unroll
            for (int ii = 0; ii < 8; ++ii)
                x[ii] = fmaxf(fmaxf(sa[2*ii], sa[2*ii+1]), fmaxf(sb[2*ii], sb[2*ii+1]));
            float pm = fmaxf(fmaxf(fmaxf(x[0], x[1]), fmaxf(x[2], x[3])),
                             fmaxf(fmaxf(x[4], x[5]), fmaxf(x[6], x[7])));
            pm = pairmax(pm);
            if (!__all(pm <= m + THR_RAW)) {
                float mn  = fmaxf(m, pm);
                float fac = exp2f((m - mn) * SCALE2);
                sr *= fac;
                #pragma unroll
                for (int r = 0; r < 16; ++r) { o0[r] *= fac; o1[r] *= fac; }
                m = mn; msc = m * SCALE2;
            }

            // ---- exp + tree sum ----
            #pragma unroll
            for (int r = 0; r < 16; ++r) {
                sa[r] = exp2f(sa[r]*SCALE2 - msc);
                sb[r] = exp2f(sb[r]*SCALE2 - msc);
            }
            float u[8];
            #pragma unroll
            for (int ii = 0; ii < 8; ++ii)
                u[ii] = (sa[2*ii] + sa[2*ii+1]) + (sb[2*ii] + sb[2*ii+1]);
            float ts = ((u[0]+u[1]) + (u[2]+u[3])) + ((u[4]+u[5]) + (u[6]+u[7]));
            sr += pairsum(ts);

            // ---- pack P to bf16 ----
            u32 WA[8], WB[8];
            #pragma unroll
            for (int wi = 0; wi < 8; ++wi) {
                WA[wi] = cvtpk(sa[2*wi], sa[2*wi+1]);
                WB[wi] = cvtpk(sb[2*wi], sb[2*wi+1]);
            }

            // ---- PV: O^T += V^T @ P^T (proven shfl-based cross-half pack) ----
            #pragma unroll
            for (int h32 = 0; h32 < 2; ++h32) {
                #pragma unroll
                for (int ks = 0; ks < 2; ++ks) {
                    u32 W0 = h32 ? WB[4*ks+0] : WA[4*ks+0];
                    u32 W1 = h32 ? WB[4*ks+1] : WA[4*ks+1];
                    u32 W2 = h32 ? WB[4*ks+2] : WA[4*ks+2];
                    u32 W3 = h32 ? WB[4*ks+3] : WA[4*ks+3];
                    u32 s0 = hi ? W0 : W2;
                    u32 s1 = hi ? W1 : W3;
                    u32 r0 = (u32)__shfl_xor((int)s0, 32, 64);
                    u32 r1 = (u32)__shfl_xor((int)s1, 32, 64);
                    u32x4 wv;
                    wv[0] = hi ? r0 : W0;
                    wv[1] = hi ? r1 : W1;
                    wv[2] = hi ? W2 : r0;
                    wv[3] = hi ? W3 : r1;
                    short8 pfrag = __builtin_bit_cast(short8, wv);
                    __builtin_amdgcn_s_setprio(1);
                    #pragma unroll
                    for (int dt = 0; dt < 2; ++dt) {
                        short8 vf = *reinterpret_cast<const short8*>(
                            &Vl[buf][(dt*32 + l31)*64 + ((4*h32 + 2*ks + hi) ^ ksw)*8]);
                        if (dt == 0)
                            o0 = __builtin_amdgcn_mfma_f32_32x32x16_bf16(vf, pfrag, o0, 0, 0, 0);
                        else
                            o1 = __builtin_amdgcn_mfma_f32_32x32x16_bf16(vf, pfrag, o1, 0, 0, 0);
                    }
                    __builtin_amdgcn_s_setprio(0);
                }
            }
        }
        __syncthreads();
    }

    // ---- epilogue ----
    const float inv = 1.0f / sr;
    unsigned short* orow = aout + ((size_t)b * SEQ + qrow) * D_MODEL + h*KD;
    #pragma unroll
    for (int dt = 0; dt < 2; ++dt) {
        #pragma unroll
        for (int g = 0; g < 4; ++g) {
            short4v pk;
            #pragma unroll
            for (int j = 0; j < 4; ++j) {
                float v = (dt == 0 ? o0[4*g + j] : o1[4*g + j]) * inv;
                pk[j] = (short)f2bf(v);
            }
            *reinterpret_cast<short4v*>(orow + dt*32 + 8*g + 4*hi) = pk;
        }
    }
}

// ---------------------------------------------------------------------------
extern "C" void kernel_launch(void* const* d_in, const int* in_sizes, int n_in,
                              void* d_out, int out_size, void* d_ws, size_t ws_size,
                              hipStream_t stream)
{
    const float* x      = (const float*)d_in[0];
    const float* W_attn = (const float*)d_in[1];
    const float* b_attn = (const float*)d_in[2];
    const float* W_proj = (const float*)d_in[3];
    const float* b_proj = (const float*)d_in[4];
    float* out = (float*)d_out;

    unsigned short* qkv  = (unsigned short*)d_ws;                  // [8192][3072]
    unsigned short* xbf  = qkv + (size_t)NTOK * QKV_N;             // [8192][1024] (= aout later)
    unsigned short* aout = xbf;
    unsigned short* WT   = xbf + (size_t)NTOK * D_MODEL;           // [3072][1024]
    unsigned short* WpT  = WT + (size_t)QKV_N * D_MODEL;           // [1024][1024]
    unsigned short* vtg  = WpT + (size_t)D_MODEL * D_MODEL;        // [4][16][64][2048]
    float* pres = out + (size_t)NTOK * D_MODEL;                    // [2,4,16,2048,64] f32

    cvt_kernel<<<(NTOK * D_MODEL / 8) / 256, 256, 0, stream>>>(x, xbf);
    dim3 gt1(QKV_N / 64, D_MODEL / 64);
    transpose_kernel<<<gt1, 256, 0, stream>>>(W_attn, WT, D_MODEL, QKV_N);
    dim3 gt2(D_MODEL / 64, D_MODEL / 64);
    transpose_kernel<<<gt2, 256, 0, stream>>>(W_proj, WpT, D_MODEL, D_MODEL);

    // qkv = x @ W_attn + b_attn  (+ fused V^T copy and f32 present k/v)
    dim3 g1(QKV_N / 128, NTOK / 128);
    gemm_bt_kernel<0, 1><<<g1, 256, 0, stream>>>(xbf, WT, b_attn, qkv, vtg, pres,
                                                 NTOK, QKV_N, D_MODEL);

    // causal attention (wave-paired q-tiles, shared staging, XCD-grouped)
    attn_kernel<<<512, 512, 0, stream>>>(qkv, vtg, aout);

    // out = aout @ W_proj + b_proj
    dim3 g2(D_MODEL / 128, NTOK / 128);
    gemm_bt_kernel<1, 0><<<g2, 256, 0, stream>>>(aout, WpT, b_proj, out,
                                                 nullptr, nullptr,
                                                 NTOK, D_MODEL, D_MODEL);
}

// Round 14
// 200.723 us; speedup vs baseline: 1.2751x; 1.0051x over previous
//
#include <hip/hip_runtime.h>

typedef __attribute__((ext_vector_type(8))) short short8;
typedef __attribute__((ext_vector_type(4))) short short4v;
typedef __attribute__((ext_vector_type(4))) float f32x4;
typedef __attribute__((ext_vector_type(16))) float f32x16;
typedef __attribute__((ext_vector_type(4))) unsigned int u32x4;
typedef __attribute__((ext_vector_type(2))) unsigned int u32x2;
typedef unsigned int u32;

#define D_MODEL 1024
#define HEADS 16
#define KD 64
#define SEQ 2048
#define BATCH 4
#define NTOK (BATCH*SEQ)    /* 8192 */
#define QKV_N (3*D_MODEL)   /* 3072 */

#define WAIT_VM(n) asm volatile("s_waitcnt vmcnt(" #n ")" ::: "memory")

__device__ inline float bf2f(unsigned short u) {
    unsigned x = ((unsigned)u) << 16;
    return __builtin_bit_cast(float, x);
}
__device__ inline unsigned short f2bf(float f) {
    unsigned u = __builtin_bit_cast(unsigned, f);
    u += 0x7FFFu + ((u >> 16) & 1u);
    return (unsigned short)(u >> 16);
}
__device__ __forceinline__ void gload_lds16(const unsigned short* g, unsigned short* l) {
    __builtin_amdgcn_global_load_lds(
        (const __attribute__((address_space(1))) void*)g,
        (__attribute__((address_space(3))) void*)l, 16, 0, 0);
}
__device__ __forceinline__ u32 cvtpk(float lo, float hi) {
    u32 r; asm("v_cvt_pk_bf16_f32 %0, %1, %2" : "=v"(r) : "v"(lo), "v"(hi)); return r;
}
// Half-exchange across the lane<32 / lane>=32 split.
__device__ __forceinline__ void pl32swap(u32& a, u32& b) {
#if __has_builtin(__builtin_amdgcn_permlane32_swap)
    u32x2 r = __builtin_amdgcn_permlane32_swap(a, b, 0, 0);
    a = r[0]; b = r[1];
#else
    u32 pa = (u32)__shfl_xor((int)a, 32, 64);
    u32 pb = (u32)__shfl_xor((int)b, 32, 64);
    bool hb = (threadIdx.x & 32) != 0;
    u32 na = hb ? pb : a;
    u32 nb = hb ? b : pa;
    a = na; b = nb;
#endif
}
// Order-robust reductions: correct for any half-exchange return convention.
__device__ __forceinline__ float pairmax(float x) {
    u32 a = __builtin_bit_cast(u32, x), b = a;
    pl32swap(a, b);
    return fmaxf(x, fmaxf(__builtin_bit_cast(float, a), __builtin_bit_cast(float, b)));
}
__device__ __forceinline__ float pairsum(float x) {
    u32 a = __builtin_bit_cast(u32, x), b = a;
    pl32swap(a, b);
    return __builtin_bit_cast(float, a) + __builtin_bit_cast(float, b);
}

// ---------------------------------------------------------------------------
// x (f32) -> bf16, elementwise, 8 per thread
// ---------------------------------------------------------------------------
__global__ __launch_bounds__(256) void cvt_kernel(
    const float* __restrict__ x, unsigned short* __restrict__ y)
{
    size_t i = (size_t)blockIdx.x * 256 + threadIdx.x;
    f32x4 a = *reinterpret_cast<const f32x4*>(x + i*8);
    f32x4 b = *reinterpret_cast<const f32x4*>(x + i*8 + 4);
    short8 o;
    #pragma unroll
    for (int j = 0; j < 4; ++j) { o[j] = (short)f2bf(a[j]); o[j+4] = (short)f2bf(b[j]); }
    *reinterpret_cast<short8*>(y + i*8) = o;
}

// ---------------------------------------------------------------------------
// WT[n][k] = bf16(W[k][n]); tile 64x64 via LDS
// ---------------------------------------------------------------------------
__global__ __launch_bounds__(256) void transpose_kernel(
    const float* __restrict__ W, unsigned short* __restrict__ WT, int K, int N)
{
    __shared__ unsigned short T[64][80];
    const int tid = threadIdx.x;
    const int n0 = blockIdx.x * 64, k0 = blockIdx.y * 64;

    int r  = tid >> 2;
    int cq = tid & 3;
    const float* src = W + (size_t)(k0 + r) * N + n0 + cq*16;
    #pragma unroll
    for (int q = 0; q < 4; ++q) {
        f32x4 v = *reinterpret_cast<const f32x4*>(src + q*4);
        #pragma unroll
        for (int j = 0; j < 4; ++j) T[cq*16 + q*4 + j][r] = f2bf(v[j]);
    }
    __syncthreads();
    int c  = tid >> 2;
    int rq = tid & 3;
    short8 o0 = *reinterpret_cast<const short8*>(&T[c][rq*16]);
    short8 o1 = *reinterpret_cast<const short8*>(&T[c][rq*16 + 8]);
    unsigned short* dst = WT + (size_t)(n0 + c) * K + k0 + rq*16;
    *reinterpret_cast<short8*>(dst)     = o0;
    *reinterpret_cast<short8*>(dst + 8) = o1;
}

// ---------------------------------------------------------------------------
// Y = A[M,K](bf16) @ BT[N,K]^T(bf16) + bias(f32).  128x128 tile, BK=64,
// 4 waves (2x2), 2-deep pipelined global_load_lds with COUNTED vmcnt
// (no vmcnt(0) drain in main loop), raw s_barrier, pre-swizzled source +
// swizzled ds_read. XCD-aware block swizzle.
// FUSE: also write vtg[b][h][d][s] (bf16 V^T) and f32 present k/v slices.
// ---------------------------------------------------------------------------
template<int Y_F32, int FUSE>
__global__ __launch_bounds__(256) void gemm_bt_kernel(
    const unsigned short* __restrict__ A, const unsigned short* __restrict__ BT,
    const float* __restrict__ bias, void* __restrict__ Yv,
    unsigned short* __restrict__ vtg, float* __restrict__ pres,
    int M, int N, int K)
{
    __shared__ unsigned short sA[2][128*64];
    __shared__ unsigned short sB[2][128*64];

    const int tid = threadIdx.x, lane = tid & 63, w = tid >> 6;
    const int l15 = lane & 15, lg = lane >> 4;

    const int nwg = gridDim.x * gridDim.y;
    const int bid = blockIdx.y * gridDim.x + blockIdx.x;
    const int swz = (bid & 7) * (nwg >> 3) + (bid >> 3);
    const int n0 = (swz % gridDim.x) * 128;
    const int m0 = (swz / gridDim.x) * 128;

    const int wr = w >> 1, wc = w & 1;

    f32x4 acc[4][4];
    #pragma unroll
    for (int m = 0; m < 4; ++m)
        #pragma unroll
        for (int n = 0; n < 4; ++n) acc[m][n] = f32x4{0,0,0,0};

    const int ldrow = (lane >> 3);
    const int slot  = lane & 7;
    const int nkt = K >> 6;

    // prologue: stage k-tiles 0 and 1 (16 glds in flight per thread)
    #pragma unroll
    for (int i = 0; i < 4; ++i) {
        int kb  = w*4 + i;
        int row = kb*8 + ldrow;
        int sc  = slot ^ (row & 7);
        gload_lds16(&A [(size_t)(m0 + row) * K + sc*8], &sA[0][kb*512]);
        gload_lds16(&BT[(size_t)(n0 + row) * K + sc*8], &sB[0][kb*512]);
    }
    #pragma unroll
    for (int i = 0; i < 4; ++i) {
        int kb  = w*4 + i;
        int row = kb*8 + ldrow;
        int sc  = slot ^ (row & 7);
        gload_lds16(&A [(size_t)(m0 + row) * K + 64 + sc*8], &sA[1][kb*512]);
        gload_lds16(&BT[(size_t)(n0 + row) * K + 64 + sc*8], &sB[1][kb*512]);
    }

    for (int kt = 0; kt < nkt; ++kt) {
        const int buf = kt & 1;

        // wait for tile kt's own loads (oldest 8); keep tile kt+1's in flight
        if (kt == nkt - 1) { WAIT_VM(0); } else { WAIT_VM(8); }
        __builtin_amdgcn_sched_barrier(0);
        __builtin_amdgcn_s_barrier();   // all waves' tile-kt loads landed

        #pragma unroll
        for (int kk = 0; kk < 2; ++kk) {
            short8 af[4], bfr[4];
            #pragma unroll
            for (int m = 0; m < 4; ++m) {
                int row = wr*64 + m*16 + l15;
                int ch  = (4*kk + lg) ^ (row & 7);
                af[m] = *reinterpret_cast<const short8*>(&sA[buf][row*64 + ch*8]);
            }
            #pragma unroll
            for (int n = 0; n < 4; ++n) {
                int row = wc*64 + n*16 + l15;
                int ch  = (4*kk + lg) ^ (row & 7);
                bfr[n] = *reinterpret_cast<const short8*>(&sB[buf][row*64 + ch*8]);
            }
            __builtin_amdgcn_s_setprio(1);
            #pragma unroll
            for (int m = 0; m < 4; ++m)
                #pragma unroll
                for (int n = 0; n < 4; ++n)
                    acc[m][n] = __builtin_amdgcn_mfma_f32_16x16x32_bf16(
                        af[m], bfr[n], acc[m][n], 0, 0, 0);
            __builtin_amdgcn_s_setprio(0);
        }

        __builtin_amdgcn_s_barrier();   // all waves done reading buf
        __builtin_amdgcn_sched_barrier(0);
        if (kt + 2 < nkt) {             // prefetch tile kt+2 into freed buf
            const int k2 = (kt + 2) << 6;
            #pragma unroll
            for (int i = 0; i < 4; ++i) {
                int kb  = w*4 + i;
                int row = kb*8 + ldrow;
                int sc  = slot ^ (row & 7);
                gload_lds16(&A [(size_t)(m0 + row) * K + k2 + sc*8], &sA[buf][kb*512]);
                gload_lds16(&BT[(size_t)(n0 + row) * K + k2 + sc*8], &sB[buf][kb*512]);
            }
        }
    }

    #pragma unroll
    for (int n = 0; n < 4; ++n) {
        int col = n0 + wc*64 + n*16 + l15;
        float bv = bias[col];
        #pragma unroll
        for (int m = 0; m < 4; ++m) {
            int row0 = m0 + wr*64 + m*16 + lg*4;
            float v0 = acc[m][n][0] + bv;
            float v1 = acc[m][n][1] + bv;
            float v2 = acc[m][n][2] + bv;
            float v3 = acc[m][n][3] + bv;
            if (Y_F32) {
                float* Y = (float*)Yv;
                Y[(size_t)(row0+0) * N + col] = v0;
                Y[(size_t)(row0+1) * N + col] = v1;
                Y[(size_t)(row0+2) * N + col] = v2;
                Y[(size_t)(row0+3) * N + col] = v3;
            } else {
                unsigned short* Y = (unsigned short*)Yv;
                Y[(size_t)(row0+0) * N + col] = f2bf(v0);
                Y[(size_t)(row0+1) * N + col] = f2bf(v1);
                Y[(size_t)(row0+2) * N + col] = f2bf(v2);
                Y[(size_t)(row0+3) * N + col] = f2bf(v3);
            }
            if (FUSE && n0 < D_MODEL) {
                int hh = col >> 6, dd = col & 63;
                int bb = row0 >> 11, ss = row0 & (SEQ - 1);
                short4v pk;
                pk[0] = (short)f2bf(v0); pk[1] = (short)f2bf(v1);
                pk[2] = (short)f2bf(v2); pk[3] = (short)f2bf(v3);
                *reinterpret_cast<short4v*>(
                    vtg + (((size_t)bb*HEADS + hh)*KD + dd)*SEQ + ss) = pk;
                float* pv = pres + (size_t)BATCH*HEADS*SEQ*KD
                          + (((size_t)bb*HEADS + hh)*SEQ + ss)*KD + dd;
                pv[0] = v0; pv[KD] = v1; pv[2*KD] = v2; pv[3*KD] = v3;
            }
            if (FUSE && n0 >= 2*D_MODEL) {
                int rel = col - 2*D_MODEL;
                int hh = rel >> 6, dd = rel & 63;
                int bb = row0 >> 11, ss = row0 & (SEQ - 1);
                float* pk2 = pres + (((size_t)bb*HEADS + hh)*SEQ + ss)*KD + dd;
                pk2[0] = v0; pk2[KD] = v1; pk2[2*KD] = v2; pk2[3*KD] = v3;
            }
        }
    }
}

// ---------------------------------------------------------------------------
// Flash attention, swapped-operand 32x32 MFMA, merged 64-key stage.
// WAVE-PAIRED q-tiles with shared K/V staging (8 waves: 0-3 -> A=2i,
// 4-7 -> B=2i+1). 2-deep pipelined staging with COUNTED vmcnt (no
// vmcnt(0) drain in loop), raw s_barrier.
// 512 blocks, biggest pair first; XCD-grouped (bid&63=(b,h)).
// ---------------------------------------------------------------------------
__global__ __launch_bounds__(512) void attn_kernel(
    const unsigned short* __restrict__ qkv,
    const unsigned short* __restrict__ vtg,
    unsigned short* __restrict__ aout)
{
    __shared__ unsigned short Kl[2][64*64];   // [key][d-chunk swz]
    __shared__ unsigned short Vl[2][64*64];   // [d][key-chunk swz]

    const int tid  = threadIdx.x;
    const int lane = tid & 63;
    const int w    = tid >> 6;          // 0..7
    const int wg   = w >> 2;            // 0: tile A, 1: tile B
    const int wl   = w & 3;             // wave within tile group
    const int l31  = lane & 31, hi = lane >> 5;

    const int bid = blockIdx.x;         // 0..511
    const int hb  = bid & 63;           // (b,h): xcd = hb & 7
    const int i   = 7 - (bid >> 6);     // 7..0 : biggest pairs first
    const int qb  = 2*i + wg;           // this wave-group's q-tile
    const int h = hb & 15, b = hb >> 4;

    const unsigned short* base  = qkv + (size_t)b * SEQ * QKV_N;
    const unsigned short* vbase = vtg + ((size_t)b * HEADS + h) * KD * SEQ;
    const int qoff = D_MODEL + h*KD;
    const int koff = 2*D_MODEL + h*KD;

    const float SCALE2 = 0.125f * 1.44269504088896f;   // 0.18034
    const float THR_RAW = 44.36f;                      // 8 / SCALE2

    const int ldrow = lane >> 3;
    const int slot  = lane & 7;
    const int ksw   = l31 & 7;

    const int q0 = qb * 128;
    const int qrow  = q0 + wl*32 + l31;
    const int qminw = q0 + wl*32;

    short8 qf[4];
    #pragma unroll
    for (int ks = 0; ks < 4; ++ks)
        qf[ks] = *reinterpret_cast<const short8*>(
            base + (size_t)qrow * QKV_N + qoff + ks*16 + hi*8);

    f32x16 o0, o1;
    #pragma unroll
    for (int r = 0; r < 16; ++r) { o0[r] = 0.f; o1[r] = 0.f; }
    float m = -1e30f, msc = -1e30f * 0.180336887f, sr = 0.f;

    const int nt = 4*i + 4;             // covers B's (2i+1) causal range; >= 4

    // prologue: stage tiles 0 and 1 (wave w stages rows w*8..w*8+7)
    {
        int row = w*8 + ldrow, sc = slot ^ (row & 7);
        gload_lds16(&base[(size_t)row * QKV_N + koff + sc*8], &Kl[0][w*512]);
        gload_lds16(&vbase[(size_t)row * SEQ + sc*8],         &Vl[0][w*512]);
        gload_lds16(&base[(size_t)(64 + row) * QKV_N + koff + sc*8], &Kl[1][w*512]);
        gload_lds16(&vbase[(size_t)row * SEQ + 64 + sc*8],           &Vl[1][w*512]);
    }

    for (int t = 0; t < nt; ++t) {
        const int buf = t & 1;

        // wait tile t's own 2 loads; keep tile t+1's in flight
        if (t == nt - 1) { WAIT_VM(0); } else { WAIT_VM(2); }
        __builtin_amdgcn_sched_barrier(0);
        __builtin_amdgcn_s_barrier();

        const int d0 = qminw - t*64;
        if (d0 > -32) {    // wave has work in this 64-key tile
            // ---- QK^T both 32-key halves ----
            f32x16 sa, sb;
            #pragma unroll
            for (int r = 0; r < 16; ++r) { sa[r] = 0.f; sb[r] = 0.f; }
            __builtin_amdgcn_s_setprio(1);
            #pragma unroll
            for (int ks = 0; ks < 4; ++ks) {
                short8 kf = *reinterpret_cast<const short8*>(
                    &Kl[buf][l31*64 + ((2*ks + hi) ^ ksw)*8]);
                sa = __builtin_amdgcn_mfma_f32_32x32x16_bf16(kf, qf[ks], sa, 0, 0, 0);
            }
            #pragma unroll
            for (int ks = 0; ks < 4; ++ks) {
                short8 kf = *reinterpret_cast<const short8*>(
                    &Kl[buf][(32 + l31)*64 + ((2*ks + hi) ^ ksw)*8]);
                sb = __builtin_amdgcn_mfma_f32_32x32x16_bf16(kf, qf[ks], sb, 0, 0, 0);
            }
            __builtin_amdgcn_s_setprio(0);

            // ---- causal mask (keys: A half = t*64+cr+4hi, B half = +32) ----
            if (d0 <= 32) {
                const int kqA = l31 + d0      - 4*hi;
                const int kqB = l31 + d0 - 32 - 4*hi;
                #pragma unroll
                for (int r = 0; r < 16; ++r) {
                    const int cr = (r & 3) + 8*(r >> 2);
                    if (d0 == 0) sa[r] = (cr <= kqA) ? sa[r] : -1e30f;
                    sb[r] = (cr <= kqB) ? sb[r] : -1e30f;
                }
            }

            // ---- max tree over 32 + cross-pair, defer-rescale ----
            float x[8];
            #pragma unroll
            for (int ii = 0; ii < 8; ++ii)
                x[ii] = fmaxf(fmaxf(sa[2*ii], sa[2*ii+1]), fmaxf(sb[2*ii], sb[2*ii+1]));
            float pm = fmaxf(fmaxf(fmaxf(x[0], x[1]), fmaxf(x[2], x[3])),
                             fmaxf(fmaxf(x[4], x[5]), fmaxf(x[6], x[7])));
            pm = pairmax(pm);
            if (!__all(pm <= m + THR_RAW)) {
                float mn  = fmaxf(m, pm);
                float fac = exp2f((m - mn) * SCALE2);
                sr *= fac;
                #pragma unroll
                for (int r = 0; r < 16; ++r) { o0[r] *= fac; o1[r] *= fac; }
                m = mn; msc = m * SCALE2;
            }

            // ---- exp + tree sum ----
            #pragma unroll
            for (int r = 0; r < 16; ++r) {
                sa[r] = exp2f(sa[r]*SCALE2 - msc);
                sb[r] = exp2f(sb[r]*SCALE2 - msc);
            }
            float u[8];
            #pragma unroll
            for (int ii = 0; ii < 8; ++ii)
                u[ii] = (sa[2*ii] + sa[2*ii+1]) + (sb[2*ii] + sb[2*ii+1]);
            float ts = ((u[0]+u[1]) + (u[2]+u[3])) + ((u[4]+u[5]) + (u[6]+u[7]));
            sr += pairsum(ts);

            // ---- pack P to bf16 ----
            u32 WA[8], WB[8];
            #pragma unroll
            for (int wi = 0; wi < 8; ++wi) {
                WA[wi] = cvtpk(sa[2*wi], sa[2*wi+1]);
                WB[wi] = cvtpk(sb[2*wi], sb[2*wi+1]);
            }

            // ---- PV: O^T += V^T @ P^T (proven shfl-based cross-half pack) ----
            #pragma unroll
            for (int h32 = 0; h32 < 2; ++h32) {
                #pragma unroll
                for (int ks = 0; ks < 2; ++ks) {
                    u32 W0 = h32 ? WB[4*ks+0] : WA[4*ks+0];
                    u32 W1 = h32 ? WB[4*ks+1] : WA[4*ks+1];
                    u32 W2 = h32 ? WB[4*ks+2] : WA[4*ks+2];
                    u32 W3 = h32 ? WB[4*ks+3] : WA[4*ks+3];
                    u32 s0 = hi ? W0 : W2;
                    u32 s1 = hi ? W1 : W3;
                    u32 r0 = (u32)__shfl_xor((int)s0, 32, 64);
                    u32 r1 = (u32)__shfl_xor((int)s1, 32, 64);
                    u32x4 wv;
                    wv[0] = hi ? r0 : W0;
                    wv[1] = hi ? r1 : W1;
                    wv[2] = hi ? W2 : r0;
                    wv[3] = hi ? W3 : r1;
                    short8 pfrag = __builtin_bit_cast(short8, wv);
                    __builtin_amdgcn_s_setprio(1);
                    #pragma unroll
                    for (int dt = 0; dt < 2; ++dt) {
                        short8 vf = *reinterpret_cast<const short8*>(
                            &Vl[buf][(dt*32 + l31)*64 + ((4*h32 + 2*ks + hi) ^ ksw)*8]);
                        if (dt == 0)
                            o0 = __builtin_amdgcn_mfma_f32_32x32x16_bf16(vf, pfrag, o0, 0, 0, 0);
                        else
                            o1 = __builtin_amdgcn_mfma_f32_32x32x16_bf16(vf, pfrag, o1, 0, 0, 0);
                    }
                    __builtin_amdgcn_s_setprio(0);
                }
            }
        }

        __builtin_amdgcn_s_barrier();   // all waves done reading buf
        __builtin_amdgcn_sched_barrier(0);
        if (t + 2 < nt) {               // prefetch tile t+2 into freed buf
            int row = w*8 + ldrow, sc = slot ^ (row & 7);
            gload_lds16(&base[(size_t)((t+2)*64 + row) * QKV_N + koff + sc*8],
                        &Kl[buf][w*512]);
            gload_lds16(&vbase[(size_t)row * SEQ + (t+2)*64 + sc*8],
                        &Vl[buf][w*512]);
        }
    }

    // ---- epilogue ----
    const float inv = 1.0f / sr;
    unsigned short* orow = aout + ((size_t)b * SEQ + qrow) * D_MODEL + h*KD;
    #pragma unroll
    for (int dt = 0; dt < 2; ++dt) {
        #pragma unroll
        for (int g = 0; g < 4; ++g) {
            short4v pk;
            #pragma unroll
            for (int j = 0; j < 4; ++j) {
                float v = (dt == 0 ? o0[4*g + j] : o1[4*g + j]) * inv;
                pk[j] = (short)f2bf(v);
            }
            *reinterpret_cast<short4v*>(orow + dt*32 + 8*g + 4*hi) = pk;
        }
    }
}

// ---------------------------------------------------------------------------
extern "C" void kernel_launch(void* const* d_in, const int* in_sizes, int n_in,
                              void* d_out, int out_size, void* d_ws, size_t ws_size,
                              hipStream_t stream)
{
    const float* x      = (const float*)d_in[0];
    const float* W_attn = (const float*)d_in[1];
    const float* b_attn = (const float*)d_in[2];
    const float* W_proj = (const float*)d_in[3];
    const float* b_proj = (const float*)d_in[4];
    float* out = (float*)d_out;

    unsigned short* qkv  = (unsigned short*)d_ws;                  // [8192][3072]
    unsigned short* xbf  = qkv + (size_t)NTOK * QKV_N;             // [8192][1024] (= aout later)
    unsigned short* aout = xbf;
    unsigned short* WT   = xbf + (size_t)NTOK * D_MODEL;           // [3072][1024]
    unsigned short* WpT  = WT + (size_t)QKV_N * D_MODEL;           // [1024][1024]
    unsigned short* vtg  = WpT + (size_t)D_MODEL * D_MODEL;        // [4][16][64][2048]
    float* pres = out + (size_t)NTOK * D_MODEL;                    // [2,4,16,2048,64] f32

    cvt_kernel<<<(NTOK * D_MODEL / 8) / 256, 256, 0, stream>>>(x, xbf);
    dim3 gt1(QKV_N / 64, D_MODEL / 64);
    transpose_kernel<<<gt1, 256, 0, stream>>>(W_attn, WT, D_MODEL, QKV_N);
    dim3 gt2(D_MODEL / 64, D_MODEL / 64);
    transpose_kernel<<<gt2, 256, 0, stream>>>(W_proj, WpT, D_MODEL, D_MODEL);

    // qkv = x @ W_attn + b_attn  (+ fused V^T copy and f32 present k/v)
    dim3 g1(QKV_N / 128, NTOK / 128);
    gemm_bt_kernel<0, 1><<<g1, 256, 0, stream>>>(xbf, WT, b_attn, qkv, vtg, pres,
                                                 NTOK, QKV_N, D_MODEL);

    // causal attention (wave-paired q-tiles, counted-vmcnt pipeline)
    attn_kernel<<<512, 512, 0, stream>>>(qkv, vtg, aout);

    // out = aout @ W_proj + b_proj
    dim3 g2(D_MODEL / 128, NTOK / 128);
    gemm_bt_kernel<1, 0><<<g2, 256, 0, stream>>>(aout, WpT, b_proj, out,
                                                 nullptr, nullptr,
                                                 NTOK, D_MODEL, D_MODEL);
}